// Round 2
// baseline (778.001 us; speedup 1.0000x reference)
//
#include <hip/hip_runtime.h>
#include <math.h>

#define NPOS 16384
#define LBAG 30
#define HDIM 512

// ---------------------------------------------------------------------------
// Kernel A: EmbeddingBag(sum) + Hardtanh(0,1) for both sides.
// grid (NPOS, 2), block 128. Each block: one bag -> 512 clipped floats.
// Writes x[pos][side*512 + h] fp32 into workspace.
// ---------------------------------------------------------------------------
__global__ void bag_clip(const int* __restrict__ stm_idx,
                         const int* __restrict__ nstm_idx,
                         const float* __restrict__ emb,
                         float* __restrict__ x) {
    const int pos  = blockIdx.x;
    const int side = blockIdx.y;
    const int t    = threadIdx.x;                 // 0..127
    const int* bag = (side == 0 ? stm_idx : nstm_idx) + pos * LBAG;

    __shared__ int sidx[LBAG];
    if (t < LBAG) sidx[t] = bag[t];
    __syncthreads();

    const int col = t << 2;                       // 128 threads * float4 = 512
    float4 acc = make_float4(0.f, 0.f, 0.f, 0.f);
#pragma unroll
    for (int l = 0; l < LBAG; ++l) {
        const float4 v = *reinterpret_cast<const float4*>(
            emb + (size_t)sidx[l] * HDIM + col);
        acc.x += v.x; acc.y += v.y; acc.z += v.z; acc.w += v.w;
    }
    acc.x = fminf(fmaxf(acc.x, 0.f), 1.f);
    acc.y = fminf(fmaxf(acc.y, 0.f), 1.f);
    acc.z = fminf(fmaxf(acc.z, 0.f), 1.f);
    acc.w = fminf(fmaxf(acc.w, 0.f), 1.f);
    *reinterpret_cast<float4*>(x + (size_t)pos * 1024 + side * HDIM + col) = acc;
}

// ---------------------------------------------------------------------------
// Kernel B: fused MLP. Layer1 as LDS-tiled fp32 GEMM (M=64/block, N=128,
// K=1024 in KC=64 chunks, 8x8 register tiles), then layer2+layer3+tanh in
// the epilogue. grid = NPOS/64 = 256 blocks, block 128 threads.
//
// Shared memory phases (flat buffer, explicit offsets; hazards separated by
// the __syncthreads() that already ends the GEMM loop / epilogue stages):
//   Phase A (GEMM):   xs[64][68]   @ 0        w1s[128][68] @ 4352
//   Phase B (MLP2/3): h1[64][132]  @ 0        w2[32][132]  @ 8448
//                     h2[64][33]   @ 12672                     (total 14784 f)
// ---------------------------------------------------------------------------
#define KC 64
#define SMEM_FLOATS 14784

__global__ __launch_bounds__(128) void mlp(
    const float* __restrict__ x,     // [NPOS][1024]
    const float* __restrict__ W1,    // [128][1024]
    const float* __restrict__ b1,    // [128]
    const float* __restrict__ W2,    // [32][128]
    const float* __restrict__ b2,    // [32]
    const float* __restrict__ W3,    // [1][32]
    const float* __restrict__ b3,    // [1]
    float* __restrict__ out)         // [NPOS]
{
    __shared__ float smem[SMEM_FLOATS];
    float* xs  = smem;                 // [64][68]
    float* w1s = smem + 64 * 68;       // [128][68]
    float* h1  = smem;                 // [64][132]
    float* w2  = smem + 64 * 132;      // [32][132]
    float* h2  = smem + 64 * 132 + 32 * 132;  // [64][33]

    const int t    = threadIdx.x;      // 0..127
    const int pblk = blockIdx.x * 64;
    const int pg   = t & 7;            // 0..7  -> positions pg + 8*i
    const int og   = t >> 3;           // 0..15 -> outputs  og + 16*j

    float acc[8][8];
#pragma unroll
    for (int i = 0; i < 8; ++i)
#pragma unroll
        for (int j = 0; j < 8; ++j) acc[i][j] = 0.f;

    for (int kc = 0; kc < 1024; kc += KC) {
        // stage x tile: 64 rows x 64 cols
#pragma unroll
        for (int i = 0; i < 8; ++i) {
            int f = t + i * 128;                 // float4 id, 0..1023
            int p = f >> 4, c4 = f & 15;
            float4 v = *reinterpret_cast<const float4*>(
                x + (size_t)(pblk + p) * 1024 + kc + c4 * 4);
            *reinterpret_cast<float4*>(&xs[p * 68 + c4 * 4]) = v;
        }
        // stage W1 tile: 128 rows x 64 cols
#pragma unroll
        for (int i = 0; i < 16; ++i) {
            int f = t + i * 128;                 // 0..2047
            int o = f >> 4, c4 = f & 15;
            float4 v = *reinterpret_cast<const float4*>(
                W1 + (size_t)o * 1024 + kc + c4 * 4);
            *reinterpret_cast<float4*>(&w1s[o * 68 + c4 * 4]) = v;
        }
        __syncthreads();
#pragma unroll
        for (int k4 = 0; k4 < 16; ++k4) {
            float4 a4[8], b4[8];
#pragma unroll
            for (int i = 0; i < 8; ++i)
                a4[i] = *reinterpret_cast<const float4*>(&xs[(pg + 8 * i) * 68 + k4 * 4]);
#pragma unroll
            for (int j = 0; j < 8; ++j)
                b4[j] = *reinterpret_cast<const float4*>(&w1s[(og + 16 * j) * 68 + k4 * 4]);
#pragma unroll
            for (int i = 0; i < 8; ++i)
#pragma unroll
                for (int j = 0; j < 8; ++j)
                    acc[i][j] += a4[i].x * b4[j].x + a4[i].y * b4[j].y +
                                 a4[i].z * b4[j].z + a4[i].w * b4[j].w;
        }
        __syncthreads();
    }

    // epilogue: bias + clip -> h1 (safe: all xs/w1s reads completed before the
    // final __syncthreads above)
#pragma unroll
    for (int j = 0; j < 8; ++j) {
        int o = og + 16 * j;
        float bb = b1[o];
#pragma unroll
        for (int i = 0; i < 8; ++i) {
            float v = acc[i][j] + bb;
            v = fminf(fmaxf(v, 0.f), 1.f);
            h1[(pg + 8 * i) * 132 + o] = v;
        }
    }
    // stage W2 (32x128) into LDS
#pragma unroll
    for (int i = 0; i < 32; ++i) {
        int f = t + i * 128;                     // 0..4095
        int o = f >> 7, k = f & 127;
        w2[o * 132 + k] = W2[o * 128 + k];
    }
    __syncthreads();

    // layer2: 64 pos x 32 out. thread -> pos p2 = t>>1, 16 outputs each.
    {
        const int p2 = t >> 1;
        const int ob = (t & 1) * 16;
        float s[16];
#pragma unroll
        for (int jj = 0; jj < 16; ++jj) s[jj] = b2[ob + jj];
#pragma unroll
        for (int k4 = 0; k4 < 32; ++k4) {
            float4 h4 = *reinterpret_cast<const float4*>(&h1[p2 * 132 + k4 * 4]);
#pragma unroll
            for (int jj = 0; jj < 16; ++jj) {
                float4 w4 = *reinterpret_cast<const float4*>(&w2[(ob + jj) * 132 + k4 * 4]);
                s[jj] += h4.x * w4.x + h4.y * w4.y + h4.z * w4.z + h4.w * w4.w;
            }
        }
#pragma unroll
        for (int jj = 0; jj < 16; ++jj) {
            float v = fminf(fmaxf(s[jj], 0.f), 1.f);
            h2[p2 * 33 + ob + jj] = v;
        }
    }
    __syncthreads();

    // layer3 + tanh: one output per position
    if (t < 64) {
        float s = b3[0];
#pragma unroll
        for (int k = 0; k < 32; ++k) s += h2[t * 33 + k] * W3[k];
        out[pblk + t] = tanhf(s);
    }
}

// ---------------------------------------------------------------------------
extern "C" void kernel_launch(void* const* d_in, const int* in_sizes, int n_in,
                              void* d_out, int out_size, void* d_ws, size_t ws_size,
                              hipStream_t stream) {
    const int*   stm_idx  = (const int*)  d_in[0];
    // d_in[1] = stm_off  (fixed arange*30, unused)
    const int*   nstm_idx = (const int*)  d_in[2];
    // d_in[3] = nstm_off (unused)
    const float* emb      = (const float*)d_in[4];
    const float* W1       = (const float*)d_in[5];
    const float* b1       = (const float*)d_in[6];
    const float* W2       = (const float*)d_in[7];
    const float* b2       = (const float*)d_in[8];
    const float* W3       = (const float*)d_in[9];
    const float* b3       = (const float*)d_in[10];
    float*       out      = (float*)d_out;
    float*       x        = (float*)d_ws;        // NPOS*1024 fp32 = 64 MB

    dim3 gA(NPOS, 2);
    bag_clip<<<gA, 128, 0, stream>>>(stm_idx, nstm_idx, emb, x);

    mlp<<<NPOS / 64, 128, 0, stream>>>(x, W1, b1, W2, b2, W3, b3, out);
}

// Round 3
// 526.083 us; speedup vs baseline: 1.4789x; 1.4789x over previous
//
#include <hip/hip_runtime.h>
#include <math.h>

#define NPOS 16384
#define LBAG 30
#define HDIM 512

// ---------------------------------------------------------------------------
// Kernel A: EmbeddingBag(sum) + Hardtanh(0,1) for both sides.
// grid (NPOS, 2), block 128. Each block: one bag -> 512 clipped floats.
// ---------------------------------------------------------------------------
__global__ void bag_clip(const int* __restrict__ stm_idx,
                         const int* __restrict__ nstm_idx,
                         const float* __restrict__ emb,
                         float* __restrict__ x) {
    const int pos  = blockIdx.x;
    const int side = blockIdx.y;
    const int t    = threadIdx.x;                 // 0..127
    const int* bag = (side == 0 ? stm_idx : nstm_idx) + pos * LBAG;

    __shared__ int sidx[LBAG];
    if (t < LBAG) sidx[t] = bag[t];
    __syncthreads();

    const int col = t << 2;                       // 128 threads * float4 = 512
    float4 acc = make_float4(0.f, 0.f, 0.f, 0.f);
#pragma unroll
    for (int l = 0; l < LBAG; ++l) {
        const float4 v = *reinterpret_cast<const float4*>(
            emb + (size_t)sidx[l] * HDIM + col);
        acc.x += v.x; acc.y += v.y; acc.z += v.z; acc.w += v.w;
    }
    acc.x = fminf(fmaxf(acc.x, 0.f), 1.f);
    acc.y = fminf(fmaxf(acc.y, 0.f), 1.f);
    acc.z = fminf(fmaxf(acc.z, 0.f), 1.f);
    acc.w = fminf(fmaxf(acc.w, 0.f), 1.f);
    *reinterpret_cast<float4*>(x + (size_t)pos * 1024 + side * HDIM + col) = acc;
}

// ---------------------------------------------------------------------------
// Kernel B: fused MLP. Layer1 fp32 GEMM: M_TILE=32 / block of 128 threads,
// N=128, K=1024 in KC=64 chunks. Per-thread 4x8 tile:
//   positions p = pg + 8*i (pg=t&7,  i=0..3)
//   outputs   o = og + 16*j (og=t>>3, j=0..7)
// acc 32 + a4 16 + b4 32 floats ~ 110 VGPR -> no spill (r2 had VGPR=256 and
// 383 MB of scratch writes at 6% occupancy; that was the 650us).
// LDS bank check: xs rows pg (stride 68) -> banks 4*pg, 8 distinct, 8-way
// broadcast; w1s rows og+16j -> banks 4*og (16*68 % 32 == 0), 8 distinct,
// broadcast. Both conflict-free.
// grid = 512 blocks, LDS 43.5 KB -> 3 blocks/CU schedulable.
//
// Shared memory phases (flat buffer, explicit offsets):
//   Phase A (GEMM):   xs[32][68] @ 0      w1s[128][68] @ 2176   (10880 f)
//   Phase B (MLP2/3): h1[32][132] @ 0     w2[32][132] @ 4224    h2[32][33] @ 8448
// ---------------------------------------------------------------------------
#define KC 64
#define MT 32
#define SMEM_FLOATS (MT * 68 + 128 * 68)

__global__ __launch_bounds__(128) void mlp(
    const float* __restrict__ x,     // [NPOS][1024]
    const float* __restrict__ W1,    // [128][1024]
    const float* __restrict__ b1,    // [128]
    const float* __restrict__ W2,    // [32][128]
    const float* __restrict__ b2,    // [32]
    const float* __restrict__ W3,    // [1][32]
    const float* __restrict__ b3,    // [1]
    float* __restrict__ out)         // [NPOS]
{
    __shared__ float smem[SMEM_FLOATS];
    float* xs  = smem;                 // [32][68]
    float* w1s = smem + MT * 68;       // [128][68]
    float* h1  = smem;                 // [32][132]
    float* w2  = smem + 32 * 132;      // [32][132]
    float* h2  = smem + 64 * 132;      // [32][33]

    const int t    = threadIdx.x;      // 0..127
    const int pblk = blockIdx.x * MT;
    const int pg   = t & 7;            // positions pg + 8*i, i=0..3
    const int og   = t >> 3;           // outputs  og + 16*j, j=0..7

    float acc[4][8];
#pragma unroll
    for (int i = 0; i < 4; ++i)
#pragma unroll
        for (int j = 0; j < 8; ++j) acc[i][j] = 0.f;

    for (int kc = 0; kc < 1024; kc += KC) {
        // stage x tile: 32 rows x 64 cols = 512 float4, 4 per thread
#pragma unroll
        for (int i = 0; i < 4; ++i) {
            int f = t + i * 128;
            int p = f >> 4, c4 = f & 15;
            float4 v = *reinterpret_cast<const float4*>(
                x + (size_t)(pblk + p) * 1024 + kc + c4 * 4);
            *reinterpret_cast<float4*>(&xs[p * 68 + c4 * 4]) = v;
        }
        // stage W1 tile: 128 rows x 64 cols = 2048 float4, 16 per thread
#pragma unroll
        for (int i = 0; i < 16; ++i) {
            int f = t + i * 128;
            int o = f >> 4, c4 = f & 15;
            float4 v = *reinterpret_cast<const float4*>(
                W1 + (size_t)o * 1024 + kc + c4 * 4);
            *reinterpret_cast<float4*>(&w1s[o * 68 + c4 * 4]) = v;
        }
        __syncthreads();
#pragma unroll
        for (int k4 = 0; k4 < 16; ++k4) {
            float4 a4[4], b4[8];
#pragma unroll
            for (int i = 0; i < 4; ++i)
                a4[i] = *reinterpret_cast<const float4*>(&xs[(pg + 8 * i) * 68 + k4 * 4]);
#pragma unroll
            for (int j = 0; j < 8; ++j)
                b4[j] = *reinterpret_cast<const float4*>(&w1s[(og + 16 * j) * 68 + k4 * 4]);
#pragma unroll
            for (int i = 0; i < 4; ++i)
#pragma unroll
                for (int j = 0; j < 8; ++j)
                    acc[i][j] += a4[i].x * b4[j].x + a4[i].y * b4[j].y +
                                 a4[i].z * b4[j].z + a4[i].w * b4[j].w;
        }
        __syncthreads();
    }

    // epilogue: bias + clip -> h1 (xs/w1s dead after last __syncthreads)
#pragma unroll
    for (int j = 0; j < 8; ++j) {
        int o = og + 16 * j;
        float bb = b1[o];
#pragma unroll
        for (int i = 0; i < 4; ++i) {
            float v = acc[i][j] + bb;
            v = fminf(fmaxf(v, 0.f), 1.f);
            h1[(pg + 8 * i) * 132 + o] = v;
        }
    }
    // stage W2 (32x128) into LDS: 4096 floats, 32 per thread
#pragma unroll
    for (int i = 0; i < 32; ++i) {
        int f = t + i * 128;
        int o = f >> 7, k = f & 127;
        w2[o * 132 + k] = W2[o * 128 + k];
    }
    __syncthreads();

    // layer2: 32 pos x 32 out. thread -> pos p2 = t>>2, 8 outputs each.
    {
        const int p2 = t >> 2;
        const int ob = (t & 3) * 8;
        float s[8];
#pragma unroll
        for (int jj = 0; jj < 8; ++jj) s[jj] = b2[ob + jj];
#pragma unroll
        for (int k4 = 0; k4 < 32; ++k4) {
            float4 h4 = *reinterpret_cast<const float4*>(&h1[p2 * 132 + k4 * 4]);
#pragma unroll
            for (int jj = 0; jj < 8; ++jj) {
                float4 w4 = *reinterpret_cast<const float4*>(&w2[(ob + jj) * 132 + k4 * 4]);
                s[jj] += h4.x * w4.x + h4.y * w4.y + h4.z * w4.z + h4.w * w4.w;
            }
        }
#pragma unroll
        for (int jj = 0; jj < 8; ++jj) {
            float v = fminf(fmaxf(s[jj], 0.f), 1.f);
            h2[p2 * 33 + ob + jj] = v;
        }
    }
    __syncthreads();

    // layer3 + tanh: one output per position
    if (t < MT) {
        float s = b3[0];
#pragma unroll
        for (int k = 0; k < 32; ++k) s += h2[t * 33 + k] * W3[k];
        out[pblk + t] = tanhf(s);
    }
}

// ---------------------------------------------------------------------------
extern "C" void kernel_launch(void* const* d_in, const int* in_sizes, int n_in,
                              void* d_out, int out_size, void* d_ws, size_t ws_size,
                              hipStream_t stream) {
    const int*   stm_idx  = (const int*)  d_in[0];
    const int*   nstm_idx = (const int*)  d_in[2];
    const float* emb      = (const float*)d_in[4];
    const float* W1       = (const float*)d_in[5];
    const float* b1       = (const float*)d_in[6];
    const float* W2       = (const float*)d_in[7];
    const float* b2       = (const float*)d_in[8];
    const float* W3       = (const float*)d_in[9];
    const float* b3       = (const float*)d_in[10];
    float*       out      = (float*)d_out;
    float*       x        = (float*)d_ws;        // NPOS*1024 fp32 = 64 MB

    dim3 gA(NPOS, 2);
    bag_clip<<<gA, 128, 0, stream>>>(stm_idx, nstm_idx, emb, x);

    mlp<<<NPOS / MT, 128, 0, stream>>>(x, W1, b1, W2, b2, W3, b3, out);
}